// Round 1
// baseline (402.746 us; speedup 1.0000x reference)
//
#include <hip/hip_runtime.h>

typedef __bf16 bf16;
typedef __bf16 bf16x8 __attribute__((ext_vector_type(8)));
typedef float f32x4 __attribute__((ext_vector_type(4)));

#define B_ 128
#define T_ 200
#define V_ 50257
#define H_ 256
#define E_ 128
#define OOV_ 50
#define VO_ 50307          // V + OOV
#define NT_G 3142          // ceil(V/16)
#define PSTR 3144          // padded partial stride

__device__ __forceinline__ float sigmoid_(float x) { return 1.0f / (1.0f + __expf(-x)); }
__device__ __forceinline__ float tanh_(float x) { return 1.0f - 2.0f / (__expf(2.0f * x) + 1.0f); }

// K1: resolve step, build h_prev^T and gru_in^T (transposed for coalesced GEMM reads)
__global__ void k_prep(const int* step_p, const float* enc, const float* prev,
                       const float* selread, const int* dec, const float* emb,
                       const float* Wi_w, const float* Wi_b,
                       float* hT, float* ginT) {
    int b = blockIdx.x, t = threadIdx.x;
    int step = step_p[0];
    float h;
    if (step == 0) {
        float acc = Wi_b[t];
        const float* er = enc + (b * T_ + (T_ - 1)) * 512;
        const float* wr = Wi_w + t * 512;
        for (int k = 0; k < 512; ++k) acc += er[k] * wr[k];
        h = acc;
    } else {
        h = prev[b * H_ + t];
    }
    hT[t * B_ + b] = h;
    for (int k = t; k < 512; k += 256)
        ginT[k * B_ + b] = (step == 0) ? 0.0f : selread[b * 512 + k];
    if (t < E_)
        ginT[(512 + t) * B_ + b] = emb[dec[b] * E_ + t];
}

// K2: gi = gru_in @ W_ih^T + b_ih ; gh = h @ W_hh^T + b_hh  (fp32, thread per (r,b))
__global__ void k_gemm_gru(const float* W_ih, const float* b_ih,
                           const float* W_hh, const float* b_hh,
                           const float* ginT, const float* hT,
                           float* giT, float* ghT) {
    int g = blockIdx.x * 256 + threadIdx.x;
    int r = g >> 7, b = g & 127;
    float acc = b_ih[r];
    const float* w = W_ih + r * 640;
#pragma unroll 8
    for (int k = 0; k < 640; ++k) acc += w[k] * ginT[k * B_ + b];
    giT[r * B_ + b] = acc;
    float acc2 = b_hh[r];
    const float* w2 = W_hh + r * 256;
#pragma unroll 8
    for (int k = 0; k < 256; ++k) acc2 += w2[k] * hT[k * B_ + b];
    ghT[r * B_ + b] = acc2;
}

// K3: GRU cell elementwise -> decode_hidden (fp32 out + bf16 copy)
__global__ void k_gru_cell(const float* giT, const float* ghT, const float* hT,
                           float* out_dh, bf16* dhb) {
    int b = blockIdx.x, j = threadIdx.x;
    float ir = giT[j * B_ + b], iz = giT[(256 + j) * B_ + b], in_ = giT[(512 + j) * B_ + b];
    float hr = ghT[j * B_ + b], hz = ghT[(256 + j) * B_ + b], hn = ghT[(512 + j) * B_ + b];
    float hp = hT[j * B_ + b];
    float r = sigmoid_(ir + hr);
    float z = sigmoid_(iz + hz);
    float n = tanh_(in_ + r * hn);
    float h = (1.0f - z) * n + z * hp;
    out_dh[b * H_ + j] = h;
    dhb[b * H_ + j] = (bf16)h;
}

// K4: score_g via bf16 MFMA; epilogue: +bias, exp, write exp to out_prob, partial row sums
__global__ __launch_bounds__(256) void k_score_g(const bf16* dhb, const float* Wg_w,
                                                 const float* Wg_b, float* out_prob,
                                                 float* pg_part) {
    int wid = threadIdx.x >> 6, lane = threadIdx.x & 63;
    int nt = blockIdx.x * 4 + wid;
    if (nt >= NT_G) return;
    int r = lane & 15, q = lane >> 4;
    int n = nt * 16 + r;
    bool valid = n < V_;
    f32x4 acc[8];
#pragma unroll
    for (int i = 0; i < 8; ++i) acc[i] = (f32x4){0.f, 0.f, 0.f, 0.f};
#pragma unroll
    for (int s = 0; s < 8; ++s) {
        int kb = s * 32 + q * 8;
        bf16x8 bfr;
        if (valid) {
            const float* wp = Wg_w + n * 256 + kb;
            float4 w0 = *(const float4*)wp;
            float4 w1 = *(const float4*)(wp + 4);
            bfr[0] = (bf16)w0.x; bfr[1] = (bf16)w0.y; bfr[2] = (bf16)w0.z; bfr[3] = (bf16)w0.w;
            bfr[4] = (bf16)w1.x; bfr[5] = (bf16)w1.y; bfr[6] = (bf16)w1.z; bfr[7] = (bf16)w1.w;
        } else {
#pragma unroll
            for (int j = 0; j < 8; ++j) bfr[j] = (bf16)0.0f;
        }
#pragma unroll
        for (int mt = 0; mt < 8; ++mt) {
            bf16x8 a = *(const bf16x8*)(dhb + (mt * 16 + r) * H_ + kb);
            acc[mt] = __builtin_amdgcn_mfma_f32_16x16x32_bf16(a, bfr, acc[mt], 0, 0, 0);
        }
    }
    float wgb = valid ? Wg_b[n] : 0.0f;
#pragma unroll
    for (int mt = 0; mt < 8; ++mt) {
#pragma unroll
        for (int rg = 0; rg < 4; ++rg) {
            int row = mt * 16 + q * 4 + rg;
            float e = valid ? __expf(acc[mt][rg] + wgb) : 0.0f;
            if (valid) out_prob[row * VO_ + n] = e;
            float sred = e;
            sred += __shfl_xor(sred, 1);
            sred += __shfl_xor(sred, 2);
            sred += __shfl_xor(sred, 4);
            sred += __shfl_xor(sred, 8);
            if (r == 0) pg_part[row * PSTR + nt] = sred;
        }
    }
}

// K5: enc_proj = tanh(enc @ Wc^T + Wc_b) as one 25600x256x512 bf16 MFMA GEMM -> bf16
__global__ __launch_bounds__(256) void k_proj(const float* enc, const float* Wc_w,
                                              const float* Wc_b, bf16* proj) {
    int wid = threadIdx.x >> 6, lane = threadIdx.x & 63;
    int mt = blockIdx.x * 4 + wid;   // 0..1599
    int r = lane & 15, q = lane >> 4;
    int m0 = mt * 16;
    f32x4 acc[16];
#pragma unroll
    for (int i = 0; i < 16; ++i) acc[i] = (f32x4){0.f, 0.f, 0.f, 0.f};
#pragma unroll 4
    for (int s = 0; s < 16; ++s) {
        int kb = s * 32 + q * 8;
        const float* ap = enc + (m0 + r) * 512 + kb;
        float4 a0 = *(const float4*)ap;
        float4 a1 = *(const float4*)(ap + 4);
        bf16x8 af;
        af[0] = (bf16)a0.x; af[1] = (bf16)a0.y; af[2] = (bf16)a0.z; af[3] = (bf16)a0.w;
        af[4] = (bf16)a1.x; af[5] = (bf16)a1.y; af[6] = (bf16)a1.z; af[7] = (bf16)a1.w;
#pragma unroll
        for (int nt = 0; nt < 16; ++nt) {
            const float* wp = Wc_w + (nt * 16 + r) * 512 + kb;
            float4 w0 = *(const float4*)wp;
            float4 w1 = *(const float4*)(wp + 4);
            bf16x8 bfr;
            bfr[0] = (bf16)w0.x; bfr[1] = (bf16)w0.y; bfr[2] = (bf16)w0.z; bfr[3] = (bf16)w0.w;
            bfr[4] = (bf16)w1.x; bfr[5] = (bf16)w1.y; bfr[6] = (bf16)w1.z; bfr[7] = (bf16)w1.w;
            acc[nt] = __builtin_amdgcn_mfma_f32_16x16x32_bf16(af, bfr, acc[nt], 0, 0, 0);
        }
    }
#pragma unroll
    for (int nt = 0; nt < 16; ++nt) {
        int n = nt * 16 + r;
        float bias = Wc_b[n];
#pragma unroll
        for (int rg = 0; rg < 4; ++rg) {
            int row = m0 + q * 4 + rg;
            proj[row * H_ + n] = (bf16)tanh_(acc[nt][rg] + bias);
        }
    }
}

// K6: score_c[b][t] = tanh(dot(proj[b,t], dh[b])) + mask; exp; block row-sum
__global__ void k_score_c(const bf16* proj, const bf16* dhb, const int* idxs,
                          float* expc, float* csum) {
    __shared__ float red[256];
    int b = blockIdx.x, t = threadIdx.x;
    float e = 0.0f;
    if (t < T_) {
        const bf16* pr = proj + (b * T_ + t) * H_;
        const bf16* dv = dhb + b * H_;
        float acc = 0.0f;
#pragma unroll
        for (int c = 0; c < 32; ++c) {
            bf16x8 p = *(const bf16x8*)(pr + c * 8);
            bf16x8 d = *(const bf16x8*)(dv + c * 8);
#pragma unroll
            for (int j = 0; j < 8; ++j) acc += (float)p[j] * (float)d[j];
        }
        float sc = tanh_(acc);
        if (idxs[b * T_ + t] == 0) sc -= 10000.0f;
        e = __expf(sc);
        expc[b * T_ + t] = e;
    }
    red[t] = e;
    __syncthreads();
    for (int s = 128; s > 0; s >>= 1) {
        if (t < s) red[t] += red[t + s];
        __syncthreads();
    }
    if (t == 0) csum[b] = red[0];
}

// K7: rowsum = sum(pg_part) + csum ; inv = 1/rowsum
__global__ void k_rowsum(const float* pg_part, const float* csum, float* inv) {
    __shared__ float red[256];
    int b = blockIdx.x, t = threadIdx.x;
    float s = 0.0f;
    for (int nt = t; nt < NT_G; nt += 256) s += pg_part[b * PSTR + nt];
    red[t] = s;
    __syncthreads();
    for (int k = 128; k > 0; k >>= 1) {
        if (t < k) red[t] += red[t + k];
        __syncthreads();
    }
    if (t == 0) inv[b] = 1.0f / (red[0] + csum[b]);
}

// K8: normalize expg in place (float4 over flat region), fill OOV pad with 1e-4
__global__ void k_norm(float* out_prob, const float* inv) {
    int i4 = blockIdx.x * 256 + threadIdx.x;
    if (i4 >= (B_ * VO_ / 4)) return;
    float4 vv = ((const float4*)out_prob)[i4];
    float r[4];
    int base = i4 * 4;
#pragma unroll
    for (int c = 0; c < 4; ++c) {
        int idx = base + c;
        int b = idx / VO_;
        int v = idx - b * VO_;
        float x = (c == 0) ? vv.x : (c == 1) ? vv.y : (c == 2) ? vv.z : vv.w;
        r[c] = (v < V_) ? x * inv[b] : 1e-4f;
    }
    ((float4*)out_prob)[i4] = make_float4(r[0], r[1], r[2], r[3]);
}

// K9: scatter prob_c into out_prob; selective_read_new (sparse over matches)
__global__ void k_scatter_sel(const float* expc, const float* inv, const int* idxs,
                              const int* dec, const float* enc,
                              float* out_prob, float* out_sel) {
    __shared__ float cf[256];
    __shared__ float red[256];
    int b = blockIdx.x, t = threadIdx.x;
    int d = dec[b];
    float iv = inv[b];
    float pc = 0.0f;
    int m = 0;
    if (t < T_) {
        int ix = idxs[b * T_ + t];
        pc = expc[b * T_ + t] * iv;
        atomicAdd(&out_prob[b * VO_ + ix], pc);
        m = (ix == d) ? 1 : 0;
    }
    cf[t] = m ? pc : 0.0f;
    red[t] = m ? 1.0f : 0.0f;
    __syncthreads();
    for (int s = 128; s > 0; s >>= 1) {
        if (t < s) red[t] += red[t + s];
        __syncthreads();
    }
    float tot = red[0];
    float scale = (tot > 1.0f) ? 1.0f / tot : 1.0f;
    float a0 = 0.0f, a1 = 0.0f;
    for (int tt = 0; tt < T_; ++tt) {
        float c = cf[tt];
        if (c != 0.0f) {
            float w = c * scale;
            a0 += w * enc[(b * T_ + tt) * 512 + t];
            a1 += w * enc[(b * T_ + tt) * 512 + t + 256];
        }
    }
    out_sel[b * 512 + t] = a0;
    out_sel[b * 512 + t + 256] = a1;
}

extern "C" void kernel_launch(void* const* d_in, const int* in_sizes, int n_in,
                              void* d_out, int out_size, void* d_ws, size_t ws_size,
                              hipStream_t stream) {
    const int*   dec     = (const int*)d_in[0];
    const float* enc     = (const float*)d_in[1];
    const int*   idxs    = (const int*)d_in[2];
    const float* prev    = (const float*)d_in[3];
    const float* selread = (const float*)d_in[4];
    const int*   step_p  = (const int*)d_in[5];
    const float* emb     = (const float*)d_in[6];
    const float* W_ih    = (const float*)d_in[7];
    const float* W_hh    = (const float*)d_in[8];
    const float* b_ih    = (const float*)d_in[9];
    const float* b_hh    = (const float*)d_in[10];
    const float* Wi_w    = (const float*)d_in[11];
    const float* Wi_b    = (const float*)d_in[12];
    const float* Wg_w    = (const float*)d_in[13];
    const float* Wg_b    = (const float*)d_in[14];
    const float* Wc_w    = (const float*)d_in[15];
    const float* Wc_b    = (const float*)d_in[16];

    float* ws   = (float*)d_ws;
    float* hT   = ws;                 // 256*128
    float* ginT = ws + 32768;         // 640*128
    float* giT  = ws + 114688;        // 768*128
    float* ghT  = ws + 212992;        // 768*128
    float* inv  = ws + 311296;        // 128
    float* csum = ws + 311424;        // 128
    float* expc = ws + 311552;        // 128*200
    float* pgp  = ws + 337152;        // 128*3144
    bf16*  dhb  = (bf16*)(ws + 739584);   // 128*256 bf16
    bf16*  proj = (bf16*)(ws + 755968);   // 25600*256 bf16

    float* out      = (float*)d_out;
    float* out_prob = out;                       // 128*50307
    float* out_dh   = out + 6439296;             // 128*256
    float* out_sel  = out + 6439296 + 32768;     // 128*512

    k_prep<<<B_, 256, 0, stream>>>(step_p, enc, prev, selread, dec, emb, Wi_w, Wi_b, hT, ginT);
    k_gemm_gru<<<384, 256, 0, stream>>>(W_ih, b_ih, W_hh, b_hh, ginT, hT, giT, ghT);
    k_gru_cell<<<B_, 256, 0, stream>>>(giT, ghT, hT, out_dh, dhb);
    k_proj<<<400, 256, 0, stream>>>(enc, Wc_w, Wc_b, proj);
    k_score_g<<<786, 256, 0, stream>>>(dhb, Wg_w, Wg_b, out_prob, pgp);
    k_score_c<<<B_, 256, 0, stream>>>(proj, dhb, idxs, expc, csum);
    k_rowsum<<<B_, 256, 0, stream>>>(pgp, csum, inv);
    k_norm<<<(B_ * VO_ / 4 + 255) / 256, 256, 0, stream>>>(out_prob, inv);
    k_scatter_sel<<<B_, 256, 0, stream>>>(expc, inv, idxs, dec, enc, out_prob, out_sel);
}

// Round 2
// 287.452 us; speedup vs baseline: 1.4011x; 1.4011x over previous
//
#include <hip/hip_runtime.h>

typedef __bf16 bf16;
typedef __bf16 bf16x8 __attribute__((ext_vector_type(8)));
typedef float f32x4 __attribute__((ext_vector_type(4)));

#define B_ 128
#define T_ 200
#define V_ 50257
#define H_ 256
#define E_ 128
#define OOV_ 50
#define VO_ 50307          // V + OOV
#define NT_G 3142          // ceil(V/16)
#define PSTR 3144          // padded partial stride

__device__ __forceinline__ float sigmoid_(float x) { return 1.0f / (1.0f + __expf(-x)); }
__device__ __forceinline__ float tanh_(float x) { return 1.0f - 2.0f / (__expf(2.0f * x) + 1.0f); }

// K0: pack Wc fp32 [256 n][512 k] -> bf16 MFMA-fragment order [kc(8)][nt(16)][ks2(2)][lane(64)][8]
__global__ void k_cvt_wc(const float* Wc_w, bf16* WcPack) {
    int f = blockIdx.x * 256 + threadIdx.x;   // frag id, 16384 total (8 elems each)
    int lane = f & 63;
    int g = f >> 6;
    int ks2 = g & 1, nt = (g >> 1) & 15, kc = g >> 5;
    int r = lane & 15, q = lane >> 4;
    int n = nt * 16 + r;
    int k = kc * 64 + ks2 * 32 + q * 8;
    const float* src = Wc_w + n * 512 + k;
    float4 v0 = *(const float4*)src;
    float4 v1 = *(const float4*)(src + 4);
    bf16* d = WcPack + f * 8;
    d[0] = (bf16)v0.x; d[1] = (bf16)v0.y; d[2] = (bf16)v0.z; d[3] = (bf16)v0.w;
    d[4] = (bf16)v1.x; d[5] = (bf16)v1.y; d[6] = (bf16)v1.z; d[7] = (bf16)v1.w;
}

// K1: resolve step, build h_prev^T and gru_in^T (transposed for coalesced GEMM reads)
__global__ void k_prep(const int* step_p, const float* enc, const float* prev,
                       const float* selread, const int* dec, const float* emb,
                       const float* Wi_w, const float* Wi_b,
                       float* hT, float* ginT) {
    int b = blockIdx.x, t = threadIdx.x;
    int step = step_p[0];
    float h;
    if (step == 0) {
        float acc = Wi_b[t];
        const float* er = enc + (b * T_ + (T_ - 1)) * 512;
        const float* wr = Wi_w + t * 512;
        for (int k = 0; k < 512; ++k) acc += er[k] * wr[k];
        h = acc;
    } else {
        h = prev[b * H_ + t];
    }
    hT[t * B_ + b] = h;
    for (int k = t; k < 512; k += 256)
        ginT[k * B_ + b] = (step == 0) ? 0.0f : selread[b * 512 + k];
    if (t < E_)
        ginT[(512 + t) * B_ + b] = emb[dec[b] * E_ + t];
}

// K2: gi = gru_in @ W_ih^T + b_ih ; gh = h @ W_hh^T + b_hh  (fp32, thread per (r,b))
__global__ void k_gemm_gru(const float* W_ih, const float* b_ih,
                           const float* W_hh, const float* b_hh,
                           const float* ginT, const float* hT,
                           float* giT, float* ghT) {
    int g = blockIdx.x * 256 + threadIdx.x;
    int r = g >> 7, b = g & 127;
    float acc = b_ih[r];
    const float* w = W_ih + r * 640;
#pragma unroll 8
    for (int k = 0; k < 640; ++k) acc += w[k] * ginT[k * B_ + b];
    giT[r * B_ + b] = acc;
    float acc2 = b_hh[r];
    const float* w2 = W_hh + r * 256;
#pragma unroll 8
    for (int k = 0; k < 256; ++k) acc2 += w2[k] * hT[k * B_ + b];
    ghT[r * B_ + b] = acc2;
}

// K3: GRU cell -> decode_hidden fp32 (out) + bf16 A-fragment-packed copy for score_g
__global__ void k_gru_cell(const float* giT, const float* ghT, const float* hT,
                           float* out_dh, bf16* Apack) {
    int b = blockIdx.x, j = threadIdx.x;
    float ir = giT[j * B_ + b], iz = giT[(256 + j) * B_ + b], in_ = giT[(512 + j) * B_ + b];
    float hr = ghT[j * B_ + b], hz = ghT[(256 + j) * B_ + b], hn = ghT[(512 + j) * B_ + b];
    float hp = hT[j * B_ + b];
    float r = sigmoid_(ir + hr);
    float z = sigmoid_(iz + hz);
    float n = tanh_(in_ + r * hn);
    float h = (1.0f - z) * n + z * hp;
    out_dh[b * H_ + j] = h;
    // Apack[mt(8)][ks(8)][lane(64)][8]: m = mt*16 + (lane&15), k = ks*32 + (lane>>4)*8 + jj
    int mt = b >> 4, rr = b & 15, ks = j >> 5, q = (j >> 3) & 3, jj = j & 7;
    Apack[(((mt * 8 + ks) * 64) + (q * 16 + rr)) * 8 + jj] = (bf16)h;
}

// K4: score_g via bf16 MFMA, Wg staged through LDS (coalesced fp32 rows -> bf16)
__global__ __launch_bounds__(256) void k_score_g(const bf16* Apack, const float* Wg_w,
                                                 const float* Wg_b, float* out_prob,
                                                 float* pg_part) {
    __shared__ bf16 Bs[64 * 264];    // 64 n-rows x 256 k, stride 264 (16B-aligned rows)
    int tid = threadIdx.x;
    int blk = blockIdx.x;
    int n0 = blk * 64;
    // stage 64 rows x 256 floats, one full row (1KB) per wave-instruction
#pragma unroll
    for (int j = 0; j < 16; ++j) {
        int f = tid + j * 256;       // float4 id, 4096 total; 64 float4 per row
        int row = f >> 6;
        int c4 = f & 63;
        int n = n0 + row;
        float4 v = (n < V_) ? *(const float4*)(Wg_w + n * 256 + c4 * 4)
                            : float4{0.f, 0.f, 0.f, 0.f};
        bf16* d = Bs + row * 264 + c4 * 4;
        d[0] = (bf16)v.x; d[1] = (bf16)v.y; d[2] = (bf16)v.z; d[3] = (bf16)v.w;
    }
    __syncthreads();
    int w = tid >> 6, lane = tid & 63;
    int r = lane & 15, q = lane >> 4;
    int nt = blk * 4 + w;
    int n = n0 + w * 16 + r;
    bool valid = n < V_;
    f32x4 acc[8];
#pragma unroll
    for (int i = 0; i < 8; ++i) acc[i] = (f32x4){0.f, 0.f, 0.f, 0.f};
#pragma unroll
    for (int ks = 0; ks < 8; ++ks) {
        bf16x8 bfr = *(const bf16x8*)(Bs + (w * 16 + r) * 264 + ks * 32 + q * 8);
#pragma unroll
        for (int mt = 0; mt < 8; ++mt) {
            bf16x8 a = *(const bf16x8*)(Apack + ((mt * 8 + ks) * 64 + lane) * 8);
            acc[mt] = __builtin_amdgcn_mfma_f32_16x16x32_bf16(a, bfr, acc[mt], 0, 0, 0);
        }
    }
    float wgb = valid ? Wg_b[n] : 0.0f;
#pragma unroll
    for (int mt = 0; mt < 8; ++mt) {
#pragma unroll
        for (int rg = 0; rg < 4; ++rg) {
            int row = mt * 16 + q * 4 + rg;
            float e = valid ? __expf(acc[mt][rg] + wgb) : 0.0f;
            if (valid) out_prob[row * VO_ + n] = e;
            float sred = e;
            sred += __shfl_xor(sred, 1);
            sred += __shfl_xor(sred, 2);
            sred += __shfl_xor(sred, 4);
            sred += __shfl_xor(sred, 8);
            if (r == 0) pg_part[row * PSTR + nt] = sred;
        }
    }
}

// K5: fused enc_proj + score_c:  expc[m] = exp(tanh( sum_n tanh(enc@Wc^T+b)[m,n]*dh[bm,n] ) + mask)
__global__ __launch_bounds__(256) void k_proj_c(const float* enc, const bf16* WcPack,
                                                const float* Wc_b, const float* dh,
                                                const int* idxs, float* expc) {
    __shared__ bf16 As[64 * 80];     // 64 m-rows x 64 k, stride 80 (16B-aligned, 2-way banks)
    __shared__ bf16 Bs[16384];       // one k-chunk of WcPack, frag-packed (flat copy)
    int tid = threadIdx.x;
    int m0 = blockIdx.x * 64;
    int w = tid >> 6, lane = tid & 63;
    int r = lane & 15, q = lane >> 4;
    f32x4 acc[16];
#pragma unroll
    for (int i = 0; i < 16; ++i) acc[i] = (f32x4){0.f, 0.f, 0.f, 0.f};
    for (int kc = 0; kc < 8; ++kc) {
        __syncthreads();
        // stage A: 64 rows x 64 k fp32 -> bf16 (16 threads per row, 4 rows/wave-instr)
#pragma unroll
        for (int j = 0; j < 4; ++j) {
            int ff = tid + j * 256;
            int row = ff >> 4;       // 16 float4 per row
            int c4 = ff & 15;
            float4 v = *(const float4*)(enc + (m0 + row) * 512 + kc * 64 + c4 * 4);
            bf16* d = As + row * 80 + c4 * 4;
            d[0] = (bf16)v.x; d[1] = (bf16)v.y; d[2] = (bf16)v.z; d[3] = (bf16)v.w;
        }
        // stage B: flat 32KB copy of this k-chunk (already frag-packed)
        {
            const float4* src = (const float4*)(WcPack + kc * 16384);
            float4* dst = (float4*)Bs;
#pragma unroll
            for (int j = 0; j < 8; ++j)
                dst[tid + j * 256] = src[tid + j * 256];
        }
        __syncthreads();
#pragma unroll
        for (int ks2 = 0; ks2 < 2; ++ks2) {
            bf16x8 a = *(const bf16x8*)(As + (w * 16 + r) * 80 + ks2 * 32 + q * 8);
#pragma unroll
            for (int nt = 0; nt < 16; ++nt) {
                bf16x8 bfr = *(const bf16x8*)(Bs + ((nt * 2 + ks2) * 64 + lane) * 8);
                acc[nt] = __builtin_amdgcn_mfma_f32_16x16x32_bf16(a, bfr, acc[nt], 0, 0, 0);
            }
        }
    }
    // epilogue: tanh(+bias) * dh, reduce over n (in-lane nt, cross-lane r), tanh+mask+exp
#pragma unroll
    for (int rg = 0; rg < 4; ++rg) {
        int row = m0 + w * 16 + q * 4 + rg;
        int b = row / T_;
        float s = 0.0f;
#pragma unroll
        for (int nt = 0; nt < 16; ++nt) {
            int n = nt * 16 + r;
            float pv = tanh_(acc[nt][rg] + Wc_b[n]);
            s += pv * dh[b * H_ + n];
        }
        s += __shfl_xor(s, 1);
        s += __shfl_xor(s, 2);
        s += __shfl_xor(s, 4);
        s += __shfl_xor(s, 8);
        if (r == 0) {
            int t = row - b * T_;
            float sc = tanh_(s);
            if (idxs[b * T_ + t] == 0) sc -= 10000.0f;
            expc[row] = __expf(sc);
        }
    }
}

// K6: inv[b] = 1 / (sum_nt pg_part + sum_t expc)
__global__ void k_rowsum(const float* pg_part, const float* expc, float* inv) {
    __shared__ float red[256];
    int b = blockIdx.x, t = threadIdx.x;
    float s = 0.0f;
    for (int nt = t; nt < NT_G; nt += 256) s += pg_part[b * PSTR + nt];
    if (t < T_) s += expc[b * T_ + t];
    red[t] = s;
    __syncthreads();
    for (int k = 128; k > 0; k >>= 1) {
        if (t < k) red[t] += red[t + k];
        __syncthreads();
    }
    if (t == 0) inv[b] = 1.0f / red[0];
}

// K7: normalize expg in place (float4 over flat region), fill OOV pad with 1e-4
__global__ void k_norm(float* out_prob, const float* inv) {
    int i4 = blockIdx.x * 256 + threadIdx.x;
    if (i4 >= (B_ * VO_ / 4)) return;
    float4 vv = ((const float4*)out_prob)[i4];
    float r[4];
    int base = i4 * 4;
#pragma unroll
    for (int c = 0; c < 4; ++c) {
        int idx = base + c;
        int b = idx / VO_;
        int v = idx - b * VO_;
        float x = (c == 0) ? vv.x : (c == 1) ? vv.y : (c == 2) ? vv.z : vv.w;
        r[c] = (v < V_) ? x * inv[b] : 1e-4f;
    }
    ((float4*)out_prob)[i4] = make_float4(r[0], r[1], r[2], r[3]);
}

// K8: scatter prob_c into out_prob; selective_read_new (sparse over matches)
__global__ void k_scatter_sel(const float* expc, const float* inv, const int* idxs,
                              const int* dec, const float* enc,
                              float* out_prob, float* out_sel) {
    __shared__ float cf[256];
    __shared__ float red[256];
    int b = blockIdx.x, t = threadIdx.x;
    int d = dec[b];
    float iv = inv[b];
    float pc = 0.0f;
    int m = 0;
    if (t < T_) {
        int ix = idxs[b * T_ + t];
        pc = expc[b * T_ + t] * iv;
        atomicAdd(&out_prob[b * VO_ + ix], pc);
        m = (ix == d) ? 1 : 0;
    }
    cf[t] = m ? pc : 0.0f;
    red[t] = m ? 1.0f : 0.0f;
    __syncthreads();
    for (int s = 128; s > 0; s >>= 1) {
        if (t < s) red[t] += red[t + s];
        __syncthreads();
    }
    float tot = red[0];
    float scale = (tot > 1.0f) ? 1.0f / tot : 1.0f;
    float a0 = 0.0f, a1 = 0.0f;
    for (int tt = 0; tt < T_; ++tt) {
        float c = cf[tt];
        if (c != 0.0f) {
            float w = c * scale;
            a0 += w * enc[(b * T_ + tt) * 512 + t];
            a1 += w * enc[(b * T_ + tt) * 512 + t + 256];
        }
    }
    out_sel[b * 512 + t] = a0;
    out_sel[b * 512 + t + 256] = a1;
}

extern "C" void kernel_launch(void* const* d_in, const int* in_sizes, int n_in,
                              void* d_out, int out_size, void* d_ws, size_t ws_size,
                              hipStream_t stream) {
    const int*   dec     = (const int*)d_in[0];
    const float* enc     = (const float*)d_in[1];
    const int*   idxs    = (const int*)d_in[2];
    const float* prev    = (const float*)d_in[3];
    const float* selread = (const float*)d_in[4];
    const int*   step_p  = (const int*)d_in[5];
    const float* emb     = (const float*)d_in[6];
    const float* W_ih    = (const float*)d_in[7];
    const float* W_hh    = (const float*)d_in[8];
    const float* b_ih    = (const float*)d_in[9];
    const float* b_hh    = (const float*)d_in[10];
    const float* Wi_w    = (const float*)d_in[11];
    const float* Wi_b    = (const float*)d_in[12];
    const float* Wg_w    = (const float*)d_in[13];
    const float* Wg_b    = (const float*)d_in[14];
    const float* Wc_w    = (const float*)d_in[15];
    const float* Wc_b    = (const float*)d_in[16];

    float* ws     = (float*)d_ws;
    float* hT     = ws;                 // 32768
    float* ginT   = ws + 32768;         // 81920
    float* giT    = ws + 114688;        // 98304
    float* ghT    = ws + 212992;        // 98304
    float* inv    = ws + 311296;        // 128
    float* expc   = ws + 311552;        // 25600
    float* pgp    = ws + 337152;        // 128*3144 = 402432
    bf16*  Apack  = (bf16*)(ws + 739584);   // 32768 bf16 (64KB)
    bf16*  WcPack = (bf16*)(ws + 755968);   // 131072 bf16 (256KB)

    float* out      = (float*)d_out;
    float* out_prob = out;                       // 128*50307
    float* out_dh   = out + 6439296;             // 128*256
    float* out_sel  = out + 6439296 + 32768;     // 128*512

    k_cvt_wc<<<64, 256, 0, stream>>>(Wc_w, WcPack);
    k_prep<<<B_, 256, 0, stream>>>(step_p, enc, prev, selread, dec, emb, Wi_w, Wi_b, hT, ginT);
    k_gemm_gru<<<384, 256, 0, stream>>>(W_ih, b_ih, W_hh, b_hh, ginT, hT, giT, ghT);
    k_gru_cell<<<B_, 256, 0, stream>>>(giT, ghT, hT, out_dh, Apack);
    k_score_g<<<786, 256, 0, stream>>>(Apack, Wg_w, Wg_b, out_prob, pgp);
    k_proj_c<<<400, 256, 0, stream>>>(enc, WcPack, Wc_b, out_dh, idxs, expc);
    k_rowsum<<<B_, 256, 0, stream>>>(pgp, expc, inv);
    k_norm<<<(B_ * VO_ / 4 + 255) / 256, 256, 0, stream>>>(out_prob, inv);
    k_scatter_sel<<<B_, 256, 0, stream>>>(expc, inv, idxs, dec, enc, out_prob, out_sel);
}